// Round 2
// baseline (611.631 us; speedup 1.0000x reference)
//
#include <hip/hip_runtime.h>
#include <stdint.h>
#include <stddef.h>

#define NE 600000
#define CI 128
#define CH 256
#define BM 64
#define NTHREADS 512
#define EPSI 1e-5f

typedef __attribute__((ext_vector_type(8))) short bf8;
typedef __attribute__((ext_vector_type(4))) float f4;

__device__ __forceinline__ unsigned short f2bf(float f) {
  union { float f; uint32_t u; } v; v.f = f;
  uint32_t u = v.u;
  u += 0x7FFFu + ((u >> 16) & 1u);   // round-to-nearest-even
  return (unsigned short)(u >> 16);
}

// Pack W[K][N] f32 -> bf16 fragment layout P[(k/8)*N + n][k%8] so a wave's
// B-frag (lane l: col = nb + (l&15), k = k0 + (l>>4)*8 + j) is one 16B load.
__global__ void pack_weights(const float* __restrict__ W1a, const float* __restrict__ W1b,
                             const float* __restrict__ W2a, const float* __restrict__ W2b,
                             unsigned short* __restrict__ ws) {
  int i = blockIdx.x * 256 + threadIdx.x;
  if (i >= 4 * 32768) return;
  int m = i >> 15;
  int r = i & 32767;
  const float* W; int N; unsigned short* dst;
  if (m == 0)      { W = W1a; N = CH; dst = ws; }
  else if (m == 1) { W = W1b; N = CH; dst = ws + 32768; }
  else if (m == 2) { W = W2a; N = CI; dst = ws + 65536; }
  else             { W = W2b; N = CI; dst = ws + 98304; }
  int k, n;
  if (m < 2) { k = r >> 8; n = r & 255; } else { k = r >> 7; n = r & 127; }
  dst[(((k >> 3) * N + n) << 3) + (k & 7)] = f2bf(W[r]);
}

// LDS map (64 KB):
//   [0,16384)      sA : s-tile  bf16 [64][128]  (XOR-swizzled)
//   [16384,32768)  eA : ef-tile bf16 [64][128]  (XOR-swizzled)
//   [32768,65536)  T  : hidden  bf16 [64][256]  (XOR-swizzled)
//   overlay [0,32768): h f32 [64][128] for the norm epilogue
__global__ __launch_bounds__(NTHREADS)
void edge_fused(const float* __restrict__ node,
                const float* __restrict__ ef,
                const int* __restrict__ eidx,
                const float* __restrict__ b1a, const float* __restrict__ b2a,
                const float* __restrict__ b1b, const float* __restrict__ b2b,
                const unsigned short* __restrict__ wp,
                float* __restrict__ out) {
  __shared__ __align__(16) char smem[65536];
  const int tid = threadIdx.x;
  const int lane = tid & 63;
  const int wv = tid >> 6;
  const int eb = blockIdx.x * BM;

  // ---- phase 0: gather-sum + ef load, f32 -> bf16, swizzled LDS stores
  {
    const int r = tid >> 3;            // edge row 0..63 (8 threads/row)
    const int c0 = (tid & 7) << 4;     // 16 cols per thread
    int e = eb + r; if (e >= NE) e = NE - 1;
    const int s = eidx[e];
    const int d = eidx[NE + e];
    const float* ps = node + (size_t)s * CI + c0;
    const float* pd = node + (size_t)d * CI + c0;
    const float* pe = ef + (size_t)e * CI + c0;
    bf8 vs[2], ve[2];
#pragma unroll
    for (int h = 0; h < 2; ++h) {
#pragma unroll
      for (int j = 0; j < 8; j += 4) {
        f4 a = *(const f4*)(ps + h * 8 + j);
        f4 b = *(const f4*)(pd + h * 8 + j);
        f4 c = *(const f4*)(pe + h * 8 + j);
#pragma unroll
        for (int q = 0; q < 4; ++q) {
          vs[h][j + q] = (short)f2bf(a[q] + b[q]);
          ve[h][j + q] = (short)f2bf(c[q]);
        }
      }
    }
    const int x = (r & 7) << 4;
    const int base = r * 256 + c0 * 2;
    *(bf8*)(smem + ((base) ^ x))              = vs[0];
    *(bf8*)(smem + ((base + 16) ^ x))         = vs[1];
    *(bf8*)(smem + 16384 + ((base) ^ x))      = ve[0];
    *(bf8*)(smem + 16384 + ((base + 16) ^ x)) = ve[1];
  }
  __syncthreads();

  const int arow = lane & 15;          // A row / B col within a 16-tile
  const int kg = lane >> 4;            // k-group 0..3
  const int ax = (arow & 7) << 4;      // A-read swizzle (row%16 preserves row&7)

  // layer-1 GEMM: T = relu(X @ W1 + b1), X bf16 [64][128] in LDS, T -> LDS
  auto mlp1 = [&](int srcOff, const unsigned short* w1, const float* bias) {
    f4 acc[4][2] = {};
#pragma unroll
    for (int k0 = 0; k0 < CI; k0 += 32) {
      bf8 a[4], b[2];
#pragma unroll
      for (int mt = 0; mt < 4; ++mt) {
        int byte = (mt * 16 + arow) * 256 + k0 * 2 + kg * 16;
        a[mt] = *(const bf8*)(smem + srcOff + (byte ^ ax));
      }
#pragma unroll
      for (int nt = 0; nt < 2; ++nt) {
        int col = wv * 32 + nt * 16 + arow;
        int pk = (k0 >> 3) + kg;
        b[nt] = *(const bf8*)(w1 + ((size_t)(pk * CH + col) << 3));
      }
#pragma unroll
      for (int mt = 0; mt < 4; ++mt)
#pragma unroll
        for (int nt = 0; nt < 2; ++nt)
          acc[mt][nt] = __builtin_amdgcn_mfma_f32_16x16x32_bf16(a[mt], b[nt], acc[mt][nt], 0, 0, 0);
    }
#pragma unroll
    for (int nt = 0; nt < 2; ++nt) {
      int col = wv * 32 + nt * 16 + arow;
      float bz = bias[col];
#pragma unroll
      for (int mt = 0; mt < 4; ++mt) {
#pragma unroll
        for (int i = 0; i < 4; ++i) {
          int r2 = mt * 16 + kg * 4 + i;        // D: row=(lane>>4)*4+i
          float v = acc[mt][nt][i] + bz;
          v = v > 0.f ? v : 0.f;
          int byte = r2 * 512 + col * 2;
          *(unsigned short*)(smem + 32768 + (byte ^ ((r2 & 7) << 4))) = f2bf(v);
        }
      }
    }
  };

  // layer-2 GEMM: hacc += T @ W2, T bf16 [64][256] in LDS
  auto mlp2 = [&](const unsigned short* w2, f4* hacc) {
#pragma unroll
    for (int k0 = 0; k0 < CH; k0 += 32) {
      bf8 a[4], b;
#pragma unroll
      for (int mt = 0; mt < 4; ++mt) {
        int byte = (mt * 16 + arow) * 512 + k0 * 2 + kg * 16;
        a[mt] = *(const bf8*)(smem + 32768 + (byte ^ ax));
      }
      int col = wv * 16 + arow;
      int pk = (k0 >> 3) + kg;
      b = *(const bf8*)(w2 + ((size_t)(pk * CI + col) << 3));
#pragma unroll
      for (int mt = 0; mt < 4; ++mt)
        hacc[mt] = __builtin_amdgcn_mfma_f32_16x16x32_bf16(a[mt], b, hacc[mt], 0, 0, 0);
    }
  };

  mlp1(0, wp, b1a);                 // T1 = relu(s @ W1a + b1a)
  __syncthreads();
  f4 hacc[4] = {};
  mlp2(wp + 65536, hacc);           // h = T1 @ W2a
  __syncthreads();                  // T consumed before overwrite
  mlp1(16384, wp + 32768, b1b);     // T2 = relu(ef @ W1b + b1b)
  __syncthreads();
  mlp2(wp + 98304, hacc);           // h += T2 @ W2b

  // h + b2 -> f32 LDS overlay [0,32768)
  {
    int col = wv * 16 + arow;
    float bz = b2a[col] + b2b[col];
    float* hl = (float*)smem;
#pragma unroll
    for (int mt = 0; mt < 4; ++mt)
#pragma unroll
      for (int i = 0; i < 4; ++i) {
        int r2 = mt * 16 + kg * 4 + i;
        hl[r2 * 128 + col] = hacc[mt][i] + bz;
      }
  }
  __syncthreads();

  // ---- norm + relu + residual + store: wave wv handles rows wv*8..wv*8+7
  {
    const float* hl = (const float*)smem;
#pragma unroll
    for (int rr = 0; rr < 8; ++rr) {
      int r = wv * 8 + rr;
      float v0 = hl[r * 128 + lane];
      float v1 = hl[r * 128 + 64 + lane];
      float s = v0 + v1;
      float q = v0 * v0 + v1 * v1;
#pragma unroll
      for (int o = 32; o >= 1; o >>= 1) {
        s += __shfl_xor(s, o);
        q += __shfl_xor(q, o);
      }
      float mu = s * (1.0f / 128.0f);
      float var = q * (1.0f / 128.0f) - mu * mu;
      float rs = rsqrtf(var + EPSI);
      int e = eb + r;
      if (e < NE) {
        size_t o0 = (size_t)e * CI + lane;
        float n0 = (v0 - mu) * rs; n0 = n0 > 0.f ? n0 : 0.f;
        float n1 = (v1 - mu) * rs; n1 = n1 > 0.f ? n1 : 0.f;
        out[o0]      = ef[o0] + n0;
        out[o0 + 64] = ef[o0 + 64] + n1;
      }
    }
  }
}

extern "C" void kernel_launch(void* const* d_in, const int* in_sizes, int n_in,
                              void* d_out, int out_size, void* d_ws, size_t ws_size,
                              hipStream_t stream) {
  const float* node = (const float*)d_in[0];
  const float* ef   = (const float*)d_in[1];
  const int* eidx   = (const int*)d_in[2];
  const float* W1a = (const float*)d_in[3];
  const float* b1a = (const float*)d_in[4];
  const float* W2a = (const float*)d_in[5];
  const float* b2a = (const float*)d_in[6];
  const float* W1b = (const float*)d_in[7];
  const float* b1b = (const float*)d_in[8];
  const float* W2b = (const float*)d_in[9];
  const float* b2b = (const float*)d_in[10];
  unsigned short* wp = (unsigned short*)d_ws;
  float* outp = (float*)d_out;

  pack_weights<<<512, 256, 0, stream>>>(W1a, W1b, W2a, W2b, wp);
  edge_fused<<<(NE + BM - 1) / BM, NTHREADS, 0, stream>>>(
      node, ef, eidx, b1a, b2a, b1b, b2b, wp, outp);
}

// Round 3
// 590.895 us; speedup vs baseline: 1.0351x; 1.0351x over previous
//
#include <hip/hip_runtime.h>
#include <stdint.h>
#include <stddef.h>

#define NE 600000
#define CI 128
#define CH 256
#define EPSI 1e-5f

typedef __attribute__((ext_vector_type(8))) short bf8;
typedef __attribute__((ext_vector_type(4))) float f4;

union FragU { bf8 h; uint32_t w[4]; };

__device__ __forceinline__ unsigned short f2bf(float f) {
  union { float f; uint32_t u; } v; v.f = f;
  uint32_t u = v.u;
  u += 0x7FFFu + ((u >> 16) & 1u);   // RNE
  return (unsigned short)(u >> 16);
}

__device__ __forceinline__ uint32_t cvtpk(float lo, float hi) {
  uint32_t r;
  asm("v_cvt_pk_bf16_f32 %0, %1, %2" : "=v"(r) : "v"(lo), "v"(hi));
  return r;
}

// Weight pack (all A-operand fragments, 16B per lane per fragment):
//  P1 (layer1, per net, 64KB): u16 P1[c][tau][t][l][j]
//    = W1[cin][hid],  cin = 32t + (l>>4)*8 + j,
//      hid = 32c + 8*((l&15)>>2) + 4*tau + ((l&15)&3)   <- permuted rows so
//      D-tile tau of chunk c gives lane kg exactly hids {8kg..+3}(tau0) / {8kg+4..+7}(tau1)
//  P2 (layer2, per net, 64KB): u16 P2[mt][c][l][j]
//    = W2[hid][cout], hid = 32c + (l>>4)*8 + j, cout = 16mt + (l&15)
// ws u16 layout: [0)P1a [32768)P1b [65536)P2a [98304)P2b
__global__ void pack_weights(const float* __restrict__ W1a, const float* __restrict__ W1b,
                             const float* __restrict__ W2a, const float* __restrict__ W2b,
                             unsigned short* __restrict__ ws) {
  int i = blockIdx.x * 256 + threadIdx.x;
  if (i >= 4 * 32768) return;
  int m = i >> 15;
  int r = i & 32767;
  int j = r & 7;
  int l = (r >> 3) & 63;
  int kg = l >> 4, q = l & 15;
  float val;
  if (m < 2) {
    int t = (r >> 9) & 3;
    int tau = (r >> 11) & 1;
    int c = (r >> 12) & 7;
    int cin = 32 * t + kg * 8 + j;
    int hid = 32 * c + 8 * (q >> 2) + 4 * tau + (q & 3);
    const float* W1 = (m == 0) ? W1a : W1b;
    val = W1[cin * CH + hid];
  } else {
    int c = (r >> 9) & 7;
    int mt = (r >> 12) & 7;
    int hid = 32 * c + kg * 8 + j;
    int cout = 16 * mt + q;
    const float* W2 = (m == 2) ? W2a : W2b;
    val = W2[hid * CI + cout];
  }
  ws[(size_t)m * 32768 + r] = f2bf(val);
}

// Fully LDS-free fused kernel. Each wave owns 16 edges; each lane owns one
// edge's B-fragments (X^T) and 32 of its 128 output channels (h^T).
__global__ __launch_bounds__(256)
void edge_fused(const float* __restrict__ node,
                const float* __restrict__ ef,
                const int* __restrict__ eidx,
                const float* __restrict__ b1a, const float* __restrict__ b2a,
                const float* __restrict__ b1b, const float* __restrict__ b2b,
                const unsigned short* __restrict__ wp,
                float* __restrict__ out) {
  const int tid = threadIdx.x;
  const int lane = tid & 63;
  const int wv = tid >> 6;
  const int kg = lane >> 4;
  const int ar = lane & 15;

  const int e = blockIdx.x * 64 + wv * 16 + ar;
  const bool ok = (e < NE);
  const int ec = ok ? e : (NE - 1);

  const int si = eidx[ec];
  const int di = eidx[NE + ec];
  const float* ps = node + (size_t)si * CI;
  const float* pd = node + (size_t)di * CI;
  const float* pe = ef + (size_t)ec * CI;

  // ---- lane-local input fragments: xs = bf16(node[src]+node[dst]), xe = bf16(ef)
  FragU xs[4], xe[4];
#pragma unroll
  for (int t = 0; t < 4; ++t) {
    const int c0 = t * 32 + kg * 8;
    f4 a0 = *(const f4*)(ps + c0), a1 = *(const f4*)(ps + c0 + 4);
    f4 d0 = *(const f4*)(pd + c0), d1 = *(const f4*)(pd + c0 + 4);
    f4 e0 = *(const f4*)(pe + c0), e1 = *(const f4*)(pe + c0 + 4);
    f4 s0 = a0 + d0, s1 = a1 + d1;
    xs[t].w[0] = cvtpk(s0[0], s0[1]); xs[t].w[1] = cvtpk(s0[2], s0[3]);
    xs[t].w[2] = cvtpk(s1[0], s1[1]); xs[t].w[3] = cvtpk(s1[2], s1[3]);
    xe[t].w[0] = cvtpk(e0[0], e0[1]); xe[t].w[1] = cvtpk(e0[2], e0[3]);
    xe[t].w[2] = cvtpk(e1[0], e1[1]); xe[t].w[3] = cvtpk(e1[2], e1[3]);
  }

  // ---- h^T accumulators (lane: edge ar, couts 16mt+4kg+i), biases folded in
  f4 hacc[8];
#pragma unroll
  for (int mt = 0; mt < 8; ++mt) {
    f4 u = *(const f4*)(b2a + mt * 16 + kg * 4);
    f4 v = *(const f4*)(b2b + mt * 16 + kg * 4);
    hacc[mt] = u + v;
  }

  const int lofs = lane * 8;

  auto runnet = [&](const FragU* x, const unsigned short* P1,
                    const unsigned short* P2, const float* b1) {
#pragma unroll 1
    for (int c = 0; c < 8; ++c) {
      // layer-1 acc init = bias (permuted row map: tau0 -> hids 32c+8kg+i, tau1 -> +4)
      f4 t0 = *(const f4*)(b1 + c * 32 + kg * 8);
      f4 t1 = *(const f4*)(b1 + c * 32 + kg * 8 + 4);
      const unsigned short* p1 = P1 + c * 4096;
#pragma unroll
      for (int t = 0; t < 4; ++t) {
        bf8 a0 = *(const bf8*)(p1 + t * 512 + lofs);
        bf8 a1 = *(const bf8*)(p1 + 2048 + t * 512 + lofs);
        t0 = __builtin_amdgcn_mfma_f32_16x16x32_bf16(a0, x[t].h, t0, 0, 0, 0);
        t1 = __builtin_amdgcn_mfma_f32_16x16x32_bf16(a1, x[t].h, t1, 0, 0, 0);
      }
      // relu + pack: lane-local layer-2 B-fragment (k = 32c + kg*8 + j)
      FragU b2f;
      b2f.w[0] = cvtpk(fmaxf(t0[0], 0.f), fmaxf(t0[1], 0.f));
      b2f.w[1] = cvtpk(fmaxf(t0[2], 0.f), fmaxf(t0[3], 0.f));
      b2f.w[2] = cvtpk(fmaxf(t1[0], 0.f), fmaxf(t1[1], 0.f));
      b2f.w[3] = cvtpk(fmaxf(t1[2], 0.f), fmaxf(t1[3], 0.f));
#pragma unroll
      for (int mt = 0; mt < 8; ++mt) {
        bf8 a2 = *(const bf8*)(P2 + (mt * 8 + c) * 512 + lofs);
        hacc[mt] = __builtin_amdgcn_mfma_f32_16x16x32_bf16(a2, b2f.h, hacc[mt], 0, 0, 0);
      }
    }
  };

  runnet(xs, wp,         wp + 65536, b1a);   // h  = relu(s @ W1a + b1a) @ W2a + b2a
  runnet(xe, wp + 32768, wp + 98304, b1b);   // h += relu(ef @ W1b + b1b) @ W2b + b2b

  // ---- InstanceNorm over 128 couts: lane has 32, group {ar, ar+16, ar+32, ar+48}
  float sum = 0.f, sq = 0.f;
#pragma unroll
  for (int mt = 0; mt < 8; ++mt)
#pragma unroll
    for (int i = 0; i < 4; ++i) { float v = hacc[mt][i]; sum += v; sq += v * v; }
  sum += __shfl_xor(sum, 16); sum += __shfl_xor(sum, 32);
  sq  += __shfl_xor(sq, 16);  sq  += __shfl_xor(sq, 32);
  const float mu = sum * (1.0f / 128.0f);
  const float var = sq * (1.0f / 128.0f) - mu * mu;
  const float rs = rsqrtf(var + EPSI);

  if (ok) {
    float* po = out + (size_t)e * CI;
    const float* pr = ef + (size_t)e * CI;
#pragma unroll
    for (int mt = 0; mt < 8; ++mt) {
      f4 r = *(const f4*)(pr + mt * 16 + kg * 4);
      f4 o;
#pragma unroll
      for (int i = 0; i < 4; ++i) {
        float n = (hacc[mt][i] - mu) * rs;
        o[i] = r[i] + fmaxf(n, 0.f);
      }
      *(f4*)(po + mt * 16 + kg * 4) = o;
    }
  }
}

extern "C" void kernel_launch(void* const* d_in, const int* in_sizes, int n_in,
                              void* d_out, int out_size, void* d_ws, size_t ws_size,
                              hipStream_t stream) {
  const float* node = (const float*)d_in[0];
  const float* ef   = (const float*)d_in[1];
  const int* eidx   = (const int*)d_in[2];
  const float* W1a = (const float*)d_in[3];
  const float* b1a = (const float*)d_in[4];
  const float* W2a = (const float*)d_in[5];
  const float* b2a = (const float*)d_in[6];
  const float* W1b = (const float*)d_in[7];
  const float* b1b = (const float*)d_in[8];
  const float* W2b = (const float*)d_in[9];
  const float* b2b = (const float*)d_in[10];
  unsigned short* wp = (unsigned short*)d_ws;
  float* outp = (float*)d_out;

  pack_weights<<<512, 256, 0, stream>>>(W1a, W1b, W2a, W2b, wp);
  edge_fused<<<(NE + 63) / 64, 256, 0, stream>>>(
      node, ef, eidx, b1a, b2a, b1b, b2b, wp, outp);
}

// Round 4
// 361.686 us; speedup vs baseline: 1.6911x; 1.6337x over previous
//
#include <hip/hip_runtime.h>
#include <stdint.h>
#include <stddef.h>

#define NE 600000
#define NN 50000
#define CI 128
#define CH 256
#define EPSI 1e-5f

typedef __attribute__((ext_vector_type(8))) short bf8;
typedef __attribute__((ext_vector_type(4))) float f4;
typedef __attribute__((ext_vector_type(4))) unsigned int u4;

union FragU { bf8 h; uint32_t w[4]; };

__device__ __forceinline__ unsigned short f2bf(float f) {
  union { float f; uint32_t u; } v; v.f = f;
  uint32_t u = v.u;
  u += 0x7FFFu + ((u >> 16) & 1u);   // RNE
  return (unsigned short)(u >> 16);
}

__device__ __forceinline__ uint32_t cvtpk(float lo, float hi) {
  uint32_t r;
  asm("v_cvt_pk_bf16_f32 %0, %1, %2" : "=v"(r) : "v"(lo), "v"(hi));
  return r;
}

__device__ __forceinline__ float asf(uint32_t x) {
  union { uint32_t u; float f; } v; v.u = x; return v.f;
}

// Weight pack (verified in round 3):
//  P1 (layer1, per net, 64KB): tau-permuted so D-regs of chunk c land as
//    lane kg's hids {32c+8kg+0..7}.
//  P2 (layer2, per net, 64KB): u16 P2[mt][c][l][j] = W2[32c+(l>>4)*8+j][16mt+(l&15)]
// ws u16 layout: [0)P1a [32768)P1b [65536)P2a [98304)P2b [131072) Ua bf16 [NN][256]
__global__ void pack_weights(const float* __restrict__ W1a, const float* __restrict__ W1b,
                             const float* __restrict__ W2a, const float* __restrict__ W2b,
                             unsigned short* __restrict__ ws) {
  int i = blockIdx.x * 256 + threadIdx.x;
  if (i >= 4 * 32768) return;
  int m = i >> 15;
  int r = i & 32767;
  int j = r & 7;
  int l = (r >> 3) & 63;
  int kg = l >> 4, q = l & 15;
  float val;
  if (m < 2) {
    int t = (r >> 9) & 3;
    int tau = (r >> 11) & 1;
    int c = (r >> 12) & 7;
    int cin = 32 * t + kg * 8 + j;
    int hid = 32 * c + 8 * (q >> 2) + 4 * tau + (q & 3);
    const float* W1 = (m == 0) ? W1a : W1b;
    val = W1[cin * CH + hid];
  } else {
    int c = (r >> 9) & 7;
    int mt = (r >> 12) & 7;
    int hid = 32 * c + kg * 8 + j;
    int cout = 16 * mt + q;
    const float* W2 = (m == 2) ? W2a : W2b;
    val = W2[hid * CI + cout];
  }
  ws[(size_t)m * 32768 + r] = f2bf(val);
}

// Ua[n][hid] = bf16( node[n] @ W1a + 0.5*b1a )  (no relu; summed per edge later)
__global__ __launch_bounds__(256)
void node_pre(const float* __restrict__ node, const float* __restrict__ b1a,
              const unsigned short* __restrict__ wp, unsigned short* __restrict__ Ua) {
  const int tid = threadIdx.x;
  const int lane = tid & 63;
  const int wv = tid >> 6;
  const int kg = lane >> 4, ar = lane & 15;
  const int n0 = blockIdx.x * 64 + wv * 16 + ar;
  const bool okn = (n0 < NN);
  const int n = okn ? n0 : (NN - 1);
  const float* pn = node + (size_t)n * CI;

  FragU xn[4];
#pragma unroll
  for (int t = 0; t < 4; ++t) {
    const int c0 = t * 32 + kg * 8;
    f4 v0 = *(const f4*)(pn + c0);
    f4 v1 = *(const f4*)(pn + c0 + 4);
    xn[t].w[0] = cvtpk(v0[0], v0[1]); xn[t].w[1] = cvtpk(v0[2], v0[3]);
    xn[t].w[2] = cvtpk(v1[0], v1[1]); xn[t].w[3] = cvtpk(v1[2], v1[3]);
  }
  const int lofs = lane * 8;
#pragma unroll 1
  for (int c = 0; c < 8; ++c) {
    f4 t0 = *(const f4*)(b1a + c * 32 + kg * 8) * 0.5f;
    f4 t1 = *(const f4*)(b1a + c * 32 + kg * 8 + 4) * 0.5f;
    const unsigned short* p1 = wp + c * 4096;
#pragma unroll
    for (int t = 0; t < 4; ++t) {
      bf8 a0 = *(const bf8*)(p1 + t * 512 + lofs);
      bf8 a1 = *(const bf8*)(p1 + 2048 + t * 512 + lofs);
      t0 = __builtin_amdgcn_mfma_f32_16x16x32_bf16(a0, xn[t].h, t0, 0, 0, 0);
      t1 = __builtin_amdgcn_mfma_f32_16x16x32_bf16(a1, xn[t].h, t1, 0, 0, 0);
    }
    u4 q;
    q[0] = cvtpk(t0[0], t0[1]); q[1] = cvtpk(t0[2], t0[3]);
    q[2] = cvtpk(t1[0], t1[1]); q[3] = cvtpk(t1[2], t1[3]);
    if (okn) *(u4*)(Ua + (size_t)n * CH + c * 32 + kg * 8) = q;
  }
}

// Fused edge kernel: 1024 threads = 16 waves, 32 edges/wave (2 groups of 16).
// LDS: [0,32768) u16 = P1b copy, [32768,65536) u16 = P2b copy (128 KB).
__global__ __launch_bounds__(1024, 4)
void edge_fused(const unsigned short* __restrict__ Ua,
                const float* __restrict__ ef,
                const int* __restrict__ eidx,
                const float* __restrict__ b1b,
                const float* __restrict__ b2a, const float* __restrict__ b2b,
                const unsigned short* __restrict__ wp,
                float* __restrict__ out) {
  __shared__ __align__(16) unsigned short lw[65536];
  const int tid = threadIdx.x;
  const int lane = tid & 63;
  const int wv = tid >> 6;
  const int kg = lane >> 4, ar = lane & 15;
  const int lofs = lane * 8;

  // ---- stage W1b+W2b into LDS (barrier deferred until after phase B)
  {
    const u4* s1 = (const u4*)(wp + 32768);
    const u4* s2 = (const u4*)(wp + 98304);
    u4* l = (u4*)lw;
#pragma unroll
    for (int i = 0; i < 4; ++i) {
      int o = i * 1024 + tid;
      l[o] = s1[o];
      l[4096 + o] = s2[o];
    }
  }

  const int be = blockIdx.x * 512 + wv * 32;
  const int e0 = be + ar, e1 = be + 16 + ar;
  const int ec0 = (e0 < NE) ? e0 : (NE - 1);
  const int ec1 = (e1 < NE) ? e1 : (NE - 1);

  // ---- h^T accumulators (lane: edge ar, couts 16mt+4kg+i), b2a+b2b folded in
  f4 hacc[2][8];
#pragma unroll
  for (int mt = 0; mt < 8; ++mt) {
    f4 u = *(const f4*)(b2a + mt * 16 + kg * 4);
    f4 v = *(const f4*)(b2b + mt * 16 + kg * 4);
    hacc[0][mt] = u + v;
    hacc[1][mt] = u + v;
  }

  // ---- phase B: layer-2a. T1 = relu(Ua[src]+Ua[dst]) streamed per K-chunk;
  //      W2a A-frags from L2, shared by both groups.
  {
    const unsigned short* pUs0 = Ua + (size_t)eidx[ec0] * CH;
    const unsigned short* pUd0 = Ua + (size_t)eidx[NE + ec0] * CH;
    const unsigned short* pUs1 = Ua + (size_t)eidx[ec1] * CH;
    const unsigned short* pUd1 = Ua + (size_t)eidx[NE + ec1] * CH;
    const unsigned short* P2a = wp + 65536;
#pragma unroll 1
    for (int u = 0; u < 8; ++u) {
      const int ko = u * 32 + kg * 8;
      u4 a0 = *(const u4*)(pUs0 + ko), d0 = *(const u4*)(pUd0 + ko);
      u4 a1 = *(const u4*)(pUs1 + ko), d1 = *(const u4*)(pUd1 + ko);
      FragU tb0, tb1;
#pragma unroll
      for (int i = 0; i < 4; ++i) {
        float lo0 = asf(a0[i] << 16) + asf(d0[i] << 16);
        float hi0 = asf(a0[i] & 0xFFFF0000u) + asf(d0[i] & 0xFFFF0000u);
        tb0.w[i] = cvtpk(fmaxf(lo0, 0.f), fmaxf(hi0, 0.f));
        float lo1 = asf(a1[i] << 16) + asf(d1[i] << 16);
        float hi1 = asf(a1[i] & 0xFFFF0000u) + asf(d1[i] & 0xFFFF0000u);
        tb1.w[i] = cvtpk(fmaxf(lo1, 0.f), fmaxf(hi1, 0.f));
      }
#pragma unroll
      for (int mt = 0; mt < 8; ++mt) {
        bf8 a = *(const bf8*)(P2a + (mt * 8 + u) * 512 + lofs);
        hacc[0][mt] = __builtin_amdgcn_mfma_f32_16x16x32_bf16(a, tb0.h, hacc[0][mt], 0, 0, 0);
        hacc[1][mt] = __builtin_amdgcn_mfma_f32_16x16x32_bf16(a, tb1.h, hacc[1][mt], 0, 0, 0);
      }
    }
  }

  __syncthreads();   // LDS weights ready

  // ---- phase A: net-b from LDS weights, group-sequential
#pragma unroll
  for (int g = 0; g < 2; ++g) {
    const int ecg = g ? ec1 : ec0;
    const float* pe = ef + (size_t)ecg * CI;
    FragU xe[4];
#pragma unroll
    for (int t = 0; t < 4; ++t) {
      const int c0 = t * 32 + kg * 8;
      f4 v0 = *(const f4*)(pe + c0);
      f4 v1 = *(const f4*)(pe + c0 + 4);
      xe[t].w[0] = cvtpk(v0[0], v0[1]); xe[t].w[1] = cvtpk(v0[2], v0[3]);
      xe[t].w[2] = cvtpk(v1[0], v1[1]); xe[t].w[3] = cvtpk(v1[2], v1[3]);
    }
#pragma unroll 1
    for (int c = 0; c < 8; ++c) {
      f4 t0 = *(const f4*)(b1b + c * 32 + kg * 8);
      f4 t1 = *(const f4*)(b1b + c * 32 + kg * 8 + 4);
#pragma unroll
      for (int t = 0; t < 4; ++t) {
        bf8 a0 = *(const bf8*)(lw + c * 4096 + t * 512 + lofs);
        bf8 a1 = *(const bf8*)(lw + c * 4096 + 2048 + t * 512 + lofs);
        t0 = __builtin_amdgcn_mfma_f32_16x16x32_bf16(a0, xe[t].h, t0, 0, 0, 0);
        t1 = __builtin_amdgcn_mfma_f32_16x16x32_bf16(a1, xe[t].h, t1, 0, 0, 0);
      }
      FragU bf_;
      bf_.w[0] = cvtpk(fmaxf(t0[0], 0.f), fmaxf(t0[1], 0.f));
      bf_.w[1] = cvtpk(fmaxf(t0[2], 0.f), fmaxf(t0[3], 0.f));
      bf_.w[2] = cvtpk(fmaxf(t1[0], 0.f), fmaxf(t1[1], 0.f));
      bf_.w[3] = cvtpk(fmaxf(t1[2], 0.f), fmaxf(t1[3], 0.f));
#pragma unroll
      for (int mt = 0; mt < 8; ++mt) {
        bf8 a2 = *(const bf8*)(lw + 32768 + (mt * 8 + c) * 512 + lofs);
        hacc[g][mt] = __builtin_amdgcn_mfma_f32_16x16x32_bf16(a2, bf_.h, hacc[g][mt], 0, 0, 0);
      }
    }
  }

  // ---- phase C: InstanceNorm + relu + residual + store, per group
#pragma unroll
  for (int g = 0; g < 2; ++g) {
    float sum = 0.f, sq = 0.f;
#pragma unroll
    for (int mt = 0; mt < 8; ++mt)
#pragma unroll
      for (int i = 0; i < 4; ++i) { float v = hacc[g][mt][i]; sum += v; sq += v * v; }
    sum += __shfl_xor(sum, 16); sum += __shfl_xor(sum, 32);
    sq  += __shfl_xor(sq, 16);  sq  += __shfl_xor(sq, 32);
    const float mu = sum * (1.0f / 128.0f);
    const float var = sq * (1.0f / 128.0f) - mu * mu;
    const float rs = rsqrtf(var + EPSI);
    const int e = g ? e1 : e0;
    if (e < NE) {
      float* po = out + (size_t)e * CI;
      const float* pr = ef + (size_t)e * CI;
#pragma unroll
      for (int mt = 0; mt < 8; ++mt) {
        f4 r = *(const f4*)(pr + mt * 16 + kg * 4);
        f4 o;
#pragma unroll
        for (int i = 0; i < 4; ++i) {
          float n = (hacc[g][mt][i] - mu) * rs;
          o[i] = r[i] + fmaxf(n, 0.f);
        }
        *(f4*)(po + mt * 16 + kg * 4) = o;
      }
    }
  }
}

extern "C" void kernel_launch(void* const* d_in, const int* in_sizes, int n_in,
                              void* d_out, int out_size, void* d_ws, size_t ws_size,
                              hipStream_t stream) {
  const float* node = (const float*)d_in[0];
  const float* ef   = (const float*)d_in[1];
  const int* eidx   = (const int*)d_in[2];
  const float* W1a = (const float*)d_in[3];
  const float* b1a = (const float*)d_in[4];
  const float* W2a = (const float*)d_in[5];
  const float* b2a = (const float*)d_in[6];
  const float* W1b = (const float*)d_in[7];
  const float* b1b = (const float*)d_in[8];
  const float* W2b = (const float*)d_in[9];
  const float* b2b = (const float*)d_in[10];
  unsigned short* wp = (unsigned short*)d_ws;            // 256 KB packed weights
  unsigned short* Ua = wp + 131072;                       // 25.6 MB bf16 Ua
  float* outp = (float*)d_out;

  pack_weights<<<512, 256, 0, stream>>>(W1a, W1b, W2a, W2b, wp);
  node_pre<<<(NN + 63) / 64, 256, 0, stream>>>(node, b1a, wp, Ua);
  edge_fused<<<(NE + 511) / 512, 1024, 0, stream>>>(
      Ua, ef, eidx, b1b, b2a, b2b, wp, outp);
}